// Round 1
// baseline (796.680 us; speedup 1.0000x reference)
//
#include <hip/hip_runtime.h>

typedef _Float16 half_t;
typedef _Float16 half2_t __attribute__((ext_vector_type(2)));

#define BB 4
#define NN 1024
#define NH 8
#define KD 16
#define ID 128
#define ED 128

static constexpr size_t OUT_SZ   = (size_t)BB * NN * ED;       // 524288
static constexpr size_t ATT_SZ   = (size_t)NH * BB * NN * NN;  // 33554432
static constexpr size_t OFF_OSS  = OUT_SZ;
static constexpr size_t OFF_ST   = OUT_SZ + ATT_SZ;
static constexpr size_t HSTRIDE  = (size_t)BB * NN * NN;       // per-head stride in (h,b,n,m)

// ---------------- Kernel 1: QKV projection ----------------
// Q stored f32 (block-uniform reads later), K/V stored f16 (halve L2 traffic).
// Layout: [(b*N + n)*128 + h*16 + k]
__global__ __launch_bounds__(128) void qkv_kernel(
    const float* __restrict__ q,  const float* __restrict__ Wq,
    const float* __restrict__ Wk, const float* __restrict__ Wv,
    float* __restrict__ Qf, half_t* __restrict__ Kf, half_t* __restrict__ Vf)
{
    const int bn = blockIdx.x;           // 0..4095
    const int j  = threadIdx.x;          // 0..127 -> (h,k)
    const int h  = j >> 4, k = j & 15;

    __shared__ float qrow[ID];
    qrow[j] = q[(size_t)bn * ID + j];
    __syncthreads();

    const float* wq = Wq + h * ID * KD + k;
    const float* wk = Wk + h * ID * KD + k;
    const float* wv = Wv + h * ID * KD + k;
    float aq = 0.f, ak = 0.f, av = 0.f;
#pragma unroll
    for (int i = 0; i < ID; ++i) {
        float x = qrow[i];
        aq = fmaf(x, wq[i * KD], aq);
        ak = fmaf(x, wk[i * KD], ak);
        av = fmaf(x, wv[i * KD], av);
    }
    Qf[(size_t)bn * 128 + j] = aq;
    Kf[(size_t)bn * 128 + j] = (half_t)ak;
    Vf[(size_t)bn * 128 + j] = (half_t)av;
}

// ---------------- Kernel 2: fused logits+MLP+softmax+PV+proj + passthrough ----------------
__global__ __launch_bounds__(256) void fused_kernel(
    const float* __restrict__ oss, const float* __restrict__ st,
    const float* __restrict__ Qf,  const half_t* __restrict__ Kf,
    const half_t* __restrict__ Vf,
    const float* __restrict__ w1,  const float* __restrict__ b1,
    const float* __restrict__ w2,  const float* __restrict__ b2,
    const float* __restrict__ Wout, float* __restrict__ out)
{
    const int n   = blockIdx.x;
    const int b   = blockIdx.y;
    const int tid = threadIdx.x;

    __shared__ float lg[NH][NN];     // 32 KB: logits, then exp'd (unnormalized) attn
    __shared__ float qsh[128];
    __shared__ float sred[NH];
    __shared__ float sinv[NH];
    __shared__ float headsSh[128];

    if (tid < 128) qsh[tid] = Qf[((size_t)(b * NN + n)) * 128 + tid];
    __syncthreads();

    const size_t bn_off = ((size_t)(b * NN + n)) * NN;
    const float4* q4 = reinterpret_cast<const float4*>(qsh);

    // ---- Pass A: logits into LDS; passthrough copies inline ----
#pragma unroll 1
    for (int mi = 0; mi < 4; ++mi) {
        const int m = mi * 256 + tid;
        const uint4* kr4 = reinterpret_cast<const uint4*>(Kf + ((size_t)(b * NN + m)) * 128);

        float x[16];
#pragma unroll
        for (int h = 0; h < 8; ++h) {
            uint4 ka = kr4[h * 2 + 0];
            uint4 kb = kr4[h * 2 + 1];
            float4 qa = q4[h * 4 + 0], qb = q4[h * 4 + 1];
            float4 qc = q4[h * 4 + 2], qd = q4[h * 4 + 3];
            union { unsigned int u; half2_t h2; } c;
            float acc = 0.f;
            c.u = ka.x; acc = fmaf((float)c.h2.x, qa.x, acc); acc = fmaf((float)c.h2.y, qa.y, acc);
            c.u = ka.y; acc = fmaf((float)c.h2.x, qa.z, acc); acc = fmaf((float)c.h2.y, qa.w, acc);
            c.u = ka.z; acc = fmaf((float)c.h2.x, qb.x, acc); acc = fmaf((float)c.h2.y, qb.y, acc);
            c.u = ka.w; acc = fmaf((float)c.h2.x, qb.z, acc); acc = fmaf((float)c.h2.y, qb.w, acc);
            c.u = kb.x; acc = fmaf((float)c.h2.x, qc.x, acc); acc = fmaf((float)c.h2.y, qc.y, acc);
            c.u = kb.y; acc = fmaf((float)c.h2.x, qc.z, acc); acc = fmaf((float)c.h2.y, qc.w, acc);
            c.u = kb.z; acc = fmaf((float)c.h2.x, qd.x, acc); acc = fmaf((float)c.h2.y, qd.y, acc);
            c.u = kb.w; acc = fmaf((float)c.h2.x, qd.z, acc); acc = fmaf((float)c.h2.y, qd.w, acc);
            x[h] = acc;
        }

#pragma unroll
        for (int h = 0; h < 8; ++h) {
            const size_t idx = (size_t)h * HSTRIDE + bn_off + (size_t)m;
            float sv = st[idx];
            float ov = oss[idx];
            out[OFF_ST + idx]  = sv;   // passthrough: st_edge copy
            out[OFF_OSS + idx] = ov;   // passthrough: out_source_attn copy
            x[h]     = (x[h] + sv) * 0.25f;   // (QK + st) * 1/sqrt(16)
            x[8 + h] = ov;
        }

        // tiny MLP: 16 -> 8 (relu) -> 8 ; weights are uniform -> scalar loads
        float y[8];
#pragma unroll
        for (int o = 0; o < 8; ++o) {
            float a = b1[o];
#pragma unroll
            for (int c2 = 0; c2 < 16; ++c2) a = fmaf(x[c2], w1[o * 16 + c2], a);
            y[o] = fmaxf(a, 0.f);
        }
#pragma unroll
        for (int p = 0; p < 8; ++p) {
            float a = b2[p];
#pragma unroll
            for (int o = 0; o < 8; ++o) a = fmaf(y[o], w2[p * 8 + o], a);
            lg[p][m] = a;
        }
    }
    __syncthreads();

    // ---- softmax: max per head (32 threads per head) ----
    {
        const int p = tid >> 5, l = tid & 31;
        float mx = -3.0e38f;
#pragma unroll
        for (int j = 0; j < 32; ++j) mx = fmaxf(mx, lg[p][l + 32 * j]);
#pragma unroll
        for (int s = 16; s > 0; s >>= 1) mx = fmaxf(mx, __shfl_xor(mx, s));
        if (l == 0) sred[p] = mx;
    }
    __syncthreads();

    // ---- exp in place ----
    {
        float sm[8];
#pragma unroll
        for (int p = 0; p < 8; ++p) sm[p] = sred[p];
#pragma unroll
        for (int mi = 0; mi < 4; ++mi) {
            const int m = mi * 256 + tid;
#pragma unroll
            for (int p = 0; p < 8; ++p) lg[p][m] = __expf(lg[p][m] - sm[p]);
        }
    }
    __syncthreads();

    // ---- sum per head ----
    {
        const int p = tid >> 5, l = tid & 31;
        float s = 0.f;
#pragma unroll
        for (int j = 0; j < 32; ++j) s += lg[p][l + 32 * j];
#pragma unroll
        for (int sft = 16; sft > 0; sft >>= 1) s += __shfl_xor(s, sft);
        if (l == 0) sinv[p] = 1.0f / s;
    }
    __syncthreads();

    // ---- PV: 32 groups of 8 threads; group owns (h, 4 consecutive v) ----
    {
        const int g = tid >> 3, sub = tid & 7;
        const int hh = g >> 2;
        const int voff = hh * 16 + (g & 3) * 4;
        float a0 = 0.f, a1 = 0.f, a2 = 0.f, a3 = 0.f;
#pragma unroll 4
        for (int j = 0; j < 128; ++j) {
            const int m = sub + 8 * j;
            const float w = lg[hh][m];
            const uint2 vv = *reinterpret_cast<const uint2*>(
                Vf + ((size_t)(b * NN + m)) * 128 + voff);
            union { unsigned int u; half2_t h2; } c;
            c.u = vv.x; a0 = fmaf(w, (float)c.h2.x, a0); a1 = fmaf(w, (float)c.h2.y, a1);
            c.u = vv.y; a2 = fmaf(w, (float)c.h2.x, a2); a3 = fmaf(w, (float)c.h2.y, a3);
        }
#pragma unroll
        for (int s = 1; s < 8; s <<= 1) {
            a0 += __shfl_xor(a0, s); a1 += __shfl_xor(a1, s);
            a2 += __shfl_xor(a2, s); a3 += __shfl_xor(a3, s);
        }
        if (sub == 0) {
            const float r = sinv[hh];
            headsSh[g * 4 + 0] = a0 * r; headsSh[g * 4 + 1] = a1 * r;
            headsSh[g * 4 + 2] = a2 * r; headsSh[g * 4 + 3] = a3 * r;
        }
    }
    __syncthreads();

    // ---- output projection: out[b,n,e] = sum_hv heads[hv] * Wout[hv,e] ----
    {
        const int e = tid & 127, hf = tid >> 7;
        float a = 0.f;
#pragma unroll
        for (int hv = 0; hv < 64; ++hv) {
            const int i = hf * 64 + hv;
            a = fmaf(headsSh[i], Wout[(size_t)i * 128 + e], a);
        }
        float* red = &lg[0][0];
        red[tid] = a;
        __syncthreads();
        if (tid < 128)
            out[((size_t)(b * NN + n)) * 128 + tid] = red[tid] + red[tid + 128];
    }
}

extern "C" void kernel_launch(void* const* d_in, const int* in_sizes, int n_in,
                              void* d_out, int out_size, void* d_ws, size_t ws_size,
                              hipStream_t stream) {
    const float* q    = (const float*)d_in[0];
    const float* oss  = (const float*)d_in[1];
    const float* st   = (const float*)d_in[2];
    const float* Wq   = (const float*)d_in[3];
    const float* Wk   = (const float*)d_in[4];
    const float* Wv   = (const float*)d_in[5];
    const float* w1   = (const float*)d_in[6];
    const float* b1   = (const float*)d_in[7];
    const float* w2   = (const float*)d_in[8];
    const float* b2   = (const float*)d_in[9];
    const float* Wout = (const float*)d_in[10];
    float* out = (float*)d_out;

    float*  Qf = (float*)d_ws;                                   // 2 MB f32
    half_t* Kf = (half_t*)((char*)d_ws + 2u * 1024u * 1024u);    // 1 MB f16
    half_t* Vf = (half_t*)((char*)d_ws + 3u * 1024u * 1024u);    // 1 MB f16

    qkv_kernel<<<dim3(BB * NN), dim3(128), 0, stream>>>(q, Wq, Wk, Wv, Qf, Kf, Vf);
    fused_kernel<<<dim3(NN, BB), dim3(256), 0, stream>>>(
        oss, st, Qf, Kf, Vf, w1, b1, w2, b2, Wout, out);
}

// Round 3
// 462.549 us; speedup vs baseline: 1.7224x; 1.7224x over previous
//
#include <hip/hip_runtime.h>

typedef _Float16 half_t;
typedef _Float16 half2_t __attribute__((ext_vector_type(2)));

#define BB 4
#define NN 1024
#define NH 8
#define KD 16
#define ID 128
#define ED 128

static constexpr size_t OUT_SZ   = (size_t)BB * NN * ED;       // 524288
static constexpr size_t ATT_SZ   = (size_t)NH * BB * NN * NN;  // 33554432
static constexpr size_t OFF_OSS  = OUT_SZ;
static constexpr size_t OFF_ST   = OUT_SZ + ATT_SZ;
static constexpr size_t HSTRIDE  = (size_t)BB * NN * NN;       // per-head stride in (h,b,n,m)

#define LGP 1032   // padded logits row (floats): shifts rows by 8 banks

__device__ __forceinline__ float fdot2u(unsigned int a, unsigned int b, float c) {
    union { unsigned int u; half2_t h; } ua, ub;
    ua.u = a; ub.u = b;
    return __builtin_amdgcn_fdot2(ua.h, ub.h, c, false);
}
// pack two floats to f16x2 (RTZ) and dot against a u32-encoded f16x2
__device__ __forceinline__ float fdot2p(unsigned int a, float lo, float hi, float c) {
    union { unsigned int u; half2_t h; } ua, ub;
    ua.u = a;
    auto pk = __builtin_amdgcn_cvt_pkrtz(lo, hi);   // __fp16 x2
    __builtin_memcpy(&ub.u, &pk, 4);
    return __builtin_amdgcn_fdot2(ua.h, ub.h, c, false);
}

// ---------------- Kernel 1: QKV projection ----------------
// Q,K stored f16 [(b*N+n)*128 + h*16 + k]; V stored f16 TRANSPOSED [((b*8+h)*16+v)*N + n]
__global__ __launch_bounds__(128) void qkv_kernel(
    const float* __restrict__ q,  const float* __restrict__ Wq,
    const float* __restrict__ Wk, const float* __restrict__ Wv,
    half_t* __restrict__ Qh, half_t* __restrict__ Kf, half_t* __restrict__ Vt)
{
    const int bn = blockIdx.x;           // 0..4095
    const int j  = threadIdx.x;          // 0..127 -> (h,k)
    const int h  = j >> 4, k = j & 15;
    const int b  = bn >> 10, n = bn & 1023;

    __shared__ float qrow[ID];
    qrow[j] = q[(size_t)bn * ID + j];
    __syncthreads();

    const float* wq = Wq + h * ID * KD + k;
    const float* wk = Wk + h * ID * KD + k;
    const float* wv = Wv + h * ID * KD + k;
    float aq = 0.f, ak = 0.f, av = 0.f;
#pragma unroll
    for (int i = 0; i < ID; ++i) {
        float x = qrow[i];
        aq = fmaf(x, wq[i * KD], aq);
        ak = fmaf(x, wk[i * KD], ak);
        av = fmaf(x, wv[i * KD], av);
    }
    Qh[(size_t)bn * 128 + j] = (half_t)aq;
    Kf[(size_t)bn * 128 + j] = (half_t)ak;
    Vt[((size_t)((b * NH + h) * KD + k)) * NN + n] = (half_t)av;
}

// ---------------- Kernel 2: fused logits+MLP+softmax+PV+proj + passthrough ----------------
__global__ __launch_bounds__(256, 4) void fused_kernel(
    const float* __restrict__ oss, const float* __restrict__ st,
    const half_t* __restrict__ Qh, const half_t* __restrict__ Kf,
    const half_t* __restrict__ Vt,
    const float* __restrict__ w1,  const float* __restrict__ b1,
    const float* __restrict__ w2,  const float* __restrict__ b2,
    const float* __restrict__ Wout, float* __restrict__ out)
{
    const int n   = blockIdx.x;
    const int b   = blockIdx.y;
    const int tid = threadIdx.x;

    __shared__ float lg[NH][LGP];        // padded logits / exp'd attn
    __shared__ unsigned int qsh[64];     // 128 f16 of this row's Q
    __shared__ float sred[NH];
    __shared__ float sinv[NH];
    __shared__ float headsSh[128];

    if (tid < 64) qsh[tid] =
        reinterpret_cast<const unsigned int*>(Qh + ((size_t)(b * NN + n)) * 128)[tid];
    __syncthreads();

    const size_t bn_off = ((size_t)(b * NN + n)) * NN;
    const uint4* q4 = reinterpret_cast<const uint4*>(qsh);

    // ---- Pass A: logits into LDS; passthrough copies inline ----
#pragma unroll 1
    for (int mi = 0; mi < 4; ++mi) {
        const int m = mi * 256 + tid;
        const uint4* kr4 = reinterpret_cast<const uint4*>(Kf + ((size_t)(b * NN + m)) * 128);

        float x[16];
#pragma unroll
        for (int h = 0; h < 8; ++h) {
            uint4 ka = kr4[h * 2 + 0];
            uint4 kb = kr4[h * 2 + 1];
            uint4 qa = q4[h * 2 + 0];
            uint4 qb = q4[h * 2 + 1];
            float acc = 0.f;
            acc = fdot2u(ka.x, qa.x, acc);
            acc = fdot2u(ka.y, qa.y, acc);
            acc = fdot2u(ka.z, qa.z, acc);
            acc = fdot2u(ka.w, qa.w, acc);
            acc = fdot2u(kb.x, qb.x, acc);
            acc = fdot2u(kb.y, qb.y, acc);
            acc = fdot2u(kb.z, qb.z, acc);
            acc = fdot2u(kb.w, qb.w, acc);
            x[h] = acc;
        }

#pragma unroll
        for (int h = 0; h < 8; ++h) {
            const size_t idx = (size_t)h * HSTRIDE + bn_off + (size_t)m;
            float sv = st[idx];
            float ov = oss[idx];
            out[OFF_ST + idx]  = sv;   // passthrough: st_edge copy
            out[OFF_OSS + idx] = ov;   // passthrough: out_source_attn copy
            x[h]     = (x[h] + sv) * 0.25f;   // (QK + st) * 1/sqrt(16)
            x[8 + h] = ov;
        }

        // tiny MLP: 16 -> 8 (relu) -> 8 ; uniform weights -> scalar loads
        float y[8];
#pragma unroll
        for (int o = 0; o < 8; ++o) {
            float a = b1[o];
#pragma unroll
            for (int c2 = 0; c2 < 16; ++c2) a = fmaf(x[c2], w1[o * 16 + c2], a);
            y[o] = fmaxf(a, 0.f);
        }
#pragma unroll
        for (int p = 0; p < 8; ++p) {
            float a = b2[p];
#pragma unroll
            for (int o = 0; o < 8; ++o) a = fmaf(y[o], w2[p * 8 + o], a);
            lg[p][m] = a;
        }
    }
    __syncthreads();

    // ---- softmax: max per head (32 threads per head) ----
    {
        const int p = tid >> 5, l = tid & 31;
        float mx = -3.0e38f;
#pragma unroll
        for (int j = 0; j < 32; ++j) mx = fmaxf(mx, lg[p][l + 32 * j]);
#pragma unroll
        for (int s = 16; s > 0; s >>= 1) mx = fmaxf(mx, __shfl_xor(mx, s));
        if (l == 0) sred[p] = mx;
    }
    __syncthreads();

    // ---- exp in place ----
    {
        float sm[8];
#pragma unroll
        for (int p = 0; p < 8; ++p) sm[p] = sred[p];
#pragma unroll
        for (int mi = 0; mi < 4; ++mi) {
            const int m = mi * 256 + tid;
#pragma unroll
            for (int p = 0; p < 8; ++p) lg[p][m] = __expf(lg[p][m] - sm[p]);
        }
    }
    __syncthreads();

    // ---- sum per head ----
    {
        const int p = tid >> 5, l = tid & 31;
        float s = 0.f;
#pragma unroll
        for (int j = 0; j < 32; ++j) s += lg[p][l + 32 * j];
#pragma unroll
        for (int sft = 16; sft > 0; sft >>= 1) s += __shfl_xor(s, sft);
        if (l == 0) sinv[p] = 1.0f / s;
    }
    __syncthreads();

    // ---- PV: thread pair owns (h,v); each thread handles 512 m via fdot2 ----
    {
        const int pp = tid >> 1;          // 0..127 = h*16+v
        const int h  = pp >> 4, v = pp & 15;
        const int hf = tid & 1;
        const uint4* vt4 = reinterpret_cast<const uint4*>(
            Vt + ((size_t)((b * NH + h) * KD + v)) * NN + hf * 512);
        const float* wrow = &lg[h][hf * 512];
        float acc = 0.f;
#pragma unroll 4
        for (int j = 0; j < 64; ++j) {
            uint4 vv = vt4[j];
            float4 w0 = reinterpret_cast<const float4*>(wrow)[2 * j + 0];
            float4 w1v = reinterpret_cast<const float4*>(wrow)[2 * j + 1];
            acc = fdot2p(vv.x, w0.x, w0.y, acc);
            acc = fdot2p(vv.y, w0.z, w0.w, acc);
            acc = fdot2p(vv.z, w1v.x, w1v.y, acc);
            acc = fdot2p(vv.w, w1v.z, w1v.w, acc);
        }
        acc += __shfl_xor(acc, 1);
        if (hf == 0) headsSh[pp] = acc * sinv[h];
    }
    __syncthreads();

    // ---- output projection: out[b,n,e] = sum_hv heads[hv] * Wout[hv,e] ----
    {
        const int e = tid & 127, hf = tid >> 7;
        float a = 0.f;
#pragma unroll
        for (int hv = 0; hv < 64; ++hv) {
            const int i = hf * 64 + hv;
            a = fmaf(headsSh[i], Wout[(size_t)i * 128 + e], a);
        }
        float* red = &lg[0][0];
        red[tid] = a;
        __syncthreads();
        if (tid < 128)
            out[((size_t)(b * NN + n)) * 128 + tid] = red[tid] + red[tid + 128];
    }
}

extern "C" void kernel_launch(void* const* d_in, const int* in_sizes, int n_in,
                              void* d_out, int out_size, void* d_ws, size_t ws_size,
                              hipStream_t stream) {
    const float* q    = (const float*)d_in[0];
    const float* oss  = (const float*)d_in[1];
    const float* st   = (const float*)d_in[2];
    const float* Wq   = (const float*)d_in[3];
    const float* Wk   = (const float*)d_in[4];
    const float* Wv   = (const float*)d_in[5];
    const float* w1   = (const float*)d_in[6];
    const float* b1   = (const float*)d_in[7];
    const float* w2   = (const float*)d_in[8];
    const float* b2   = (const float*)d_in[9];
    const float* Wout = (const float*)d_in[10];
    float* out = (float*)d_out;

    half_t* Qh = (half_t*)d_ws;                                   // 1 MB f16
    half_t* Kf = (half_t*)((char*)d_ws + 1u * 1024u * 1024u);     // 1 MB f16
    half_t* Vt = (half_t*)((char*)d_ws + 2u * 1024u * 1024u);     // 1 MB f16 (transposed)

    qkv_kernel<<<dim3(BB * NN), dim3(128), 0, stream>>>(q, Wq, Wk, Wv, Qh, Kf, Vt);
    fused_kernel<<<dim3(NN, BB), dim3(256), 0, stream>>>(
        oss, st, Qh, Kf, Vt, w1, b1, w2, b2, Wout, out);
}

// Round 4
// 448.630 us; speedup vs baseline: 1.7758x; 1.0310x over previous
//
#include <hip/hip_runtime.h>

typedef _Float16 half_t;
typedef _Float16 half2_t __attribute__((ext_vector_type(2)));

#define BB 4
#define NN 1024
#define NH 8
#define KD 16
#define ID 128
#define ED 128

static constexpr size_t OUT_SZ   = (size_t)BB * NN * ED;       // 524288
static constexpr size_t ATT_SZ   = (size_t)NH * BB * NN * NN;  // 33554432
static constexpr size_t OFF_OSS  = OUT_SZ;
static constexpr size_t OFF_ST   = OUT_SZ + ATT_SZ;
static constexpr size_t HSTRIDE  = (size_t)BB * NN * NN;       // per-head stride in (h,b,n,m)

#define LGW 1032   // f16 elements per logits row (1024 + 8 pad)

__device__ __forceinline__ float fdot2u(unsigned int a, unsigned int b, float c) {
    union { unsigned int u; half2_t h; } ua, ub;
    ua.u = a; ub.u = b;
    return __builtin_amdgcn_fdot2(ua.h, ub.h, c, false);
}

// ---------------- Kernel 1: QKV projection ----------------
// Q,K stored f16 [(b*N+n)*128 + h*16 + k]; V stored f16 TRANSPOSED [((b*8+h)*16+v)*N + n]
__global__ __launch_bounds__(128) void qkv_kernel(
    const float* __restrict__ q,  const float* __restrict__ Wq,
    const float* __restrict__ Wk, const float* __restrict__ Wv,
    half_t* __restrict__ Qh, half_t* __restrict__ Kf, half_t* __restrict__ Vt)
{
    const int bn = blockIdx.x;           // 0..4095
    const int j  = threadIdx.x;          // 0..127 -> (h,k)
    const int h  = j >> 4, k = j & 15;
    const int b  = bn >> 10, n = bn & 1023;

    __shared__ float qrow[ID];
    qrow[j] = q[(size_t)bn * ID + j];
    __syncthreads();

    const float* wq = Wq + h * ID * KD + k;
    const float* wk = Wk + h * ID * KD + k;
    const float* wv = Wv + h * ID * KD + k;
    float aq = 0.f, ak = 0.f, av = 0.f;
#pragma unroll
    for (int i = 0; i < ID; ++i) {
        float x = qrow[i];
        aq = fmaf(x, wq[i * KD], aq);
        ak = fmaf(x, wk[i * KD], ak);
        av = fmaf(x, wv[i * KD], av);
    }
    Qh[(size_t)bn * 128 + j] = (half_t)aq;
    Kf[(size_t)bn * 128 + j] = (half_t)ak;
    Vt[((size_t)((b * NH + h) * KD + k)) * NN + n] = (half_t)av;
}

// ---------------- Kernel 2: fused logits+MLP+softmax+PV+proj + passthrough ----------------
__global__ __launch_bounds__(256, 6) void fused_kernel(
    const float* __restrict__ oss, const float* __restrict__ st,
    const half_t* __restrict__ Qh, const half_t* __restrict__ Kf,
    const half_t* __restrict__ Vt,
    const float* __restrict__ w1,  const float* __restrict__ b1,
    const float* __restrict__ w2,  const float* __restrict__ b2,
    const float* __restrict__ Wout, float* __restrict__ out)
{
    const int n   = blockIdx.x;
    const int b   = blockIdx.y;
    const int tid = threadIdx.x;

    __shared__ __align__(16) half_t lg[NH * LGW];   // 16.1 KB f16 logits/weights
    __shared__ unsigned int qsh[64];
    __shared__ float wred[4][8];
    __shared__ float wsum[4][8];
    __shared__ float headsSh[128];

    if (tid < 64) qsh[tid] =
        reinterpret_cast<const unsigned int*>(Qh + ((size_t)(b * NN + n)) * 128)[tid];
    __syncthreads();

    const int m0 = tid * 4;                         // thread owns m0..m0+3
    const size_t bn_off = ((size_t)(b * NN + n)) * NN;
    const uint4* kbase = reinterpret_cast<const uint4*>(Kf + ((size_t)(b * NN + m0)) * 128);
    const uint4* qv    = reinterpret_cast<const uint4*>(qsh);

    // layer-1 accumulators, streamed over h
    float y[4][8];
#pragma unroll
    for (int mo = 0; mo < 4; ++mo)
#pragma unroll
        for (int o = 0; o < 8; ++o) y[mo][o] = b1[o];

#pragma unroll 1
    for (int h = 0; h < 8; ++h) {
        const uint4 qa = qv[h * 2 + 0];
        const uint4 qb = qv[h * 2 + 1];
        const size_t idx = (size_t)h * HSTRIDE + bn_off + (size_t)m0;
        const float4 sv = *reinterpret_cast<const float4*>(st + idx);
        const float4 ov = *reinterpret_cast<const float4*>(oss + idx);
        *reinterpret_cast<float4*>(out + OFF_ST + idx)  = sv;   // st_edge passthrough
        *reinterpret_cast<float4*>(out + OFF_OSS + idx) = ov;   // oss passthrough
        const float svv[4] = {sv.x, sv.y, sv.z, sv.w};
        const float ovv[4] = {ov.x, ov.y, ov.z, ov.w};
        float w1c[8], w1o[8];                       // uniform -> SGPRs
#pragma unroll
        for (int o = 0; o < 8; ++o) { w1c[o] = w1[o * 16 + h]; w1o[o] = w1[o * 16 + 8 + h]; }
#pragma unroll
        for (int mo = 0; mo < 4; ++mo) {
            const uint4 ka = kbase[mo * 16 + h * 2 + 0];
            const uint4 kb = kbase[mo * 16 + h * 2 + 1];
            float acc = 0.f;
            acc = fdot2u(ka.x, qa.x, acc);
            acc = fdot2u(ka.y, qa.y, acc);
            acc = fdot2u(ka.z, qa.z, acc);
            acc = fdot2u(ka.w, qa.w, acc);
            acc = fdot2u(kb.x, qb.x, acc);
            acc = fdot2u(kb.y, qb.y, acc);
            acc = fdot2u(kb.z, qb.z, acc);
            acc = fdot2u(kb.w, qb.w, acc);
            const float c = (acc + svv[mo]) * 0.25f;   // (QK + st) * 1/sqrt(16)
#pragma unroll
            for (int o = 0; o < 8; ++o)
                y[mo][o] = fmaf(c, w1c[o], fmaf(ovv[mo], w1o[o], y[mo][o]));
        }
    }

    // ---- layer 2 -> f16 logits in LDS + per-thread max ----
    float lgv[8][4];
#pragma unroll
    for (int mo = 0; mo < 4; ++mo) {
        float z[8];
#pragma unroll
        for (int o = 0; o < 8; ++o) z[o] = fmaxf(y[mo][o], 0.f);
#pragma unroll
        for (int p = 0; p < 8; ++p) {
            float a = b2[p];
#pragma unroll
            for (int o = 0; o < 8; ++o) a = fmaf(z[o], w2[p * 8 + o], a);
            lgv[p][mo] = a;
        }
    }
    float tmax[8];
#pragma unroll
    for (int p = 0; p < 8; ++p) {
        union { uint2 u; half_t h4[4]; } pk;
#pragma unroll
        for (int mo = 0; mo < 4; ++mo) pk.h4[mo] = (half_t)lgv[p][mo];
        *reinterpret_cast<uint2*>(&lg[p * LGW + m0]) = pk.u;
        tmax[p] = fmaxf(fmaxf(lgv[p][0], lgv[p][1]), fmaxf(lgv[p][2], lgv[p][3]));
    }
#pragma unroll
    for (int p = 0; p < 8; ++p)
#pragma unroll
        for (int s = 32; s > 0; s >>= 1)
            tmax[p] = fmaxf(tmax[p], __shfl_xor(tmax[p], s));
    const int wv = tid >> 6;
    if ((tid & 63) == 0) {
#pragma unroll
        for (int p = 0; p < 8; ++p) wred[wv][p] = tmax[p];
    }
    __syncthreads();

    float bmax[8];
#pragma unroll
    for (int p = 0; p < 8; ++p)
        bmax[p] = fmaxf(fmaxf(wred[0][p], wred[1][p]), fmaxf(wred[2][p], wred[3][p]));

    // ---- exp in place (f16) + per-thread sums ----
    float psum[8];
#pragma unroll
    for (int p = 0; p < 8; ++p) {
        union { uint2 u; half_t h4[4]; } r;
        r.u = *reinterpret_cast<const uint2*>(&lg[p * LGW + m0]);
        const float e0 = __expf((float)r.h4[0] - bmax[p]);
        const float e1 = __expf((float)r.h4[1] - bmax[p]);
        const float e2 = __expf((float)r.h4[2] - bmax[p]);
        const float e3 = __expf((float)r.h4[3] - bmax[p]);
        psum[p] = (e0 + e1) + (e2 + e3);
        union { uint2 u; half_t h4[4]; } w;
        w.h4[0] = (half_t)e0; w.h4[1] = (half_t)e1;
        w.h4[2] = (half_t)e2; w.h4[3] = (half_t)e3;
        *reinterpret_cast<uint2*>(&lg[p * LGW + m0]) = w.u;
    }
#pragma unroll
    for (int p = 0; p < 8; ++p)
#pragma unroll
        for (int s = 32; s > 0; s >>= 1)
            psum[p] += __shfl_xor(psum[p], s);
    if ((tid & 63) == 0) {
#pragma unroll
        for (int p = 0; p < 8; ++p) wsum[wv][p] = psum[p];
    }
    __syncthreads();

    // ---- PV: thread pair owns (h,v); f16 weights straight from LDS ----
    {
        const int pp = tid >> 1;          // 0..127 = h*16+v
        const int h  = pp >> 4, v = pp & 15;
        const int hf = tid & 1;
        const uint4* vt4 = reinterpret_cast<const uint4*>(
            Vt + ((size_t)((b * NH + h) * KD + v)) * NN + hf * 512);
        const uint4* wr = reinterpret_cast<const uint4*>(&lg[h * LGW + hf * 512]);
        float acc = 0.f;
#pragma unroll 4
        for (int j = 0; j < 64; ++j) {
            const uint4 vv = vt4[j];
            const uint4 ww = wr[j];
            acc = fdot2u(vv.x, ww.x, acc);
            acc = fdot2u(vv.y, ww.y, acc);
            acc = fdot2u(vv.z, ww.z, acc);
            acc = fdot2u(vv.w, ww.w, acc);
        }
        acc += __shfl_xor(acc, 1);
        if (hf == 0) {
            const float s = (wsum[0][h] + wsum[1][h]) + (wsum[2][h] + wsum[3][h]);
            headsSh[pp] = acc * (1.0f / s);
        }
    }
    __syncthreads();

    // ---- output projection: out[b,n,e] = sum_hv heads[hv] * Wout[hv,e] ----
    {
        const int e = tid & 127, hf2 = tid >> 7;
        float a = 0.f;
#pragma unroll
        for (int hv = 0; hv < 64; ++hv) {
            const int i = hf2 * 64 + hv;
            a = fmaf(headsSh[i], Wout[(size_t)i * 128 + e], a);
        }
        float* red = reinterpret_cast<float*>(lg);
        red[tid] = a;
        __syncthreads();
        if (tid < 128)
            out[((size_t)(b * NN + n)) * 128 + tid] = red[tid] + red[tid + 128];
    }
}

extern "C" void kernel_launch(void* const* d_in, const int* in_sizes, int n_in,
                              void* d_out, int out_size, void* d_ws, size_t ws_size,
                              hipStream_t stream) {
    const float* q    = (const float*)d_in[0];
    const float* oss  = (const float*)d_in[1];
    const float* st   = (const float*)d_in[2];
    const float* Wq   = (const float*)d_in[3];
    const float* Wk   = (const float*)d_in[4];
    const float* Wv   = (const float*)d_in[5];
    const float* w1   = (const float*)d_in[6];
    const float* b1   = (const float*)d_in[7];
    const float* w2   = (const float*)d_in[8];
    const float* b2   = (const float*)d_in[9];
    const float* Wout = (const float*)d_in[10];
    float* out = (float*)d_out;

    half_t* Qh = (half_t*)d_ws;                                   // 1 MB f16
    half_t* Kf = (half_t*)((char*)d_ws + 1u * 1024u * 1024u);     // 1 MB f16
    half_t* Vt = (half_t*)((char*)d_ws + 2u * 1024u * 1024u);     // 1 MB f16 (transposed)

    qkv_kernel<<<dim3(BB * NN), dim3(128), 0, stream>>>(q, Wq, Wk, Wv, Qh, Kf, Vt);
    fused_kernel<<<dim3(NN, BB), dim3(256), 0, stream>>>(
        oss, st, Qh, Kf, Vt, w1, b1, w2, b2, Wout, out);
}

// Round 5
// 233.905 us; speedup vs baseline: 3.4060x; 1.9180x over previous
//
#include <hip/hip_runtime.h>

typedef _Float16 half_t;
typedef _Float16 half2_t __attribute__((ext_vector_type(2)));

#define BB 4
#define NN 1024
#define NH 8
#define KD 16
#define ID 128
#define ED 128

static constexpr size_t OUT_SZ   = (size_t)BB * NN * ED;       // 524288
static constexpr size_t ATT_SZ   = (size_t)NH * BB * NN * NN;  // 33554432
static constexpr size_t OFF_OSS  = OUT_SZ;
static constexpr size_t OFF_ST   = OUT_SZ + ATT_SZ;
static constexpr size_t HSTRIDE  = (size_t)BB * NN * NN;       // per-head stride in (h,b,n,m)

#define LGW 1032   // f16 elements per logits row (1024 + 8 pad)

__device__ __forceinline__ float fdot2u(unsigned int a, unsigned int b, float c) {
    union { unsigned int u; half2_t h; } ua, ub;
    ua.u = a; ub.u = b;
    return __builtin_amdgcn_fdot2(ua.h, ub.h, c, false);
}

// ---------------- Kernel 1: QKV projection ----------------
// Qh  [ (b*N+n)*128 + h*16+k ]                       (f16, natural k-pair u32 layout)
// Kp  [ ((b*8+h)*8+kp)*N + n ] u32 = (K[n][2kp],K[n][2kp+1])   (k-pair packed along n)
// Vp  [ ((b*8+h)*8+vp)*N + n ] u32 = (V[n][2vp],V[n][2vp+1])   (v-pair packed along n)
__global__ __launch_bounds__(128) void qkv_kernel(
    const float* __restrict__ q,  const float* __restrict__ Wq,
    const float* __restrict__ Wk, const float* __restrict__ Wv,
    half_t* __restrict__ Qh, half_t* __restrict__ Kp, half_t* __restrict__ Vp)
{
    const int bn = blockIdx.x;           // 0..4095
    const int j  = threadIdx.x;          // 0..127 -> (h,k)
    const int h  = j >> 4, k = j & 15;
    const int b  = bn >> 10, n = bn & 1023;

    __shared__ float qrow[ID];
    qrow[j] = q[(size_t)bn * ID + j];
    __syncthreads();

    const float* wq = Wq + h * ID * KD + k;
    const float* wk = Wk + h * ID * KD + k;
    const float* wv = Wv + h * ID * KD + k;
    float aq = 0.f, ak = 0.f, av = 0.f;
#pragma unroll
    for (int i = 0; i < ID; ++i) {
        float x = qrow[i];
        aq = fmaf(x, wq[i * KD], aq);
        ak = fmaf(x, wk[i * KD], ak);
        av = fmaf(x, wv[i * KD], av);
    }
    Qh[(size_t)bn * 128 + j] = (half_t)aq;
    const size_t pr = ((size_t)((b * NH + h) * 8 + (k >> 1)) * NN + n) * 2 + (k & 1);
    Kp[pr] = (half_t)ak;
    Vp[pr] = (half_t)av;
}

// ---------------- Kernel 2: fused logits+MLP+softmax+PV+proj + passthrough ----------------
__global__ __launch_bounds__(256, 8) void fused_kernel(
    const float* __restrict__ oss, const float* __restrict__ st,
    const half_t* __restrict__ Qh, const unsigned int* __restrict__ Kp,
    const unsigned int* __restrict__ Vp,
    const float* __restrict__ w1,  const float* __restrict__ b1,
    const float* __restrict__ w2,  const float* __restrict__ b2,
    const float* __restrict__ Wout, float* __restrict__ out)
{
    const int n   = blockIdx.x;
    const int b   = blockIdx.y;
    const int tid = threadIdx.x;

    __shared__ __align__(16) half_t lg[NH * LGW];   // 16.1 KB f16 logits/weights
    __shared__ unsigned int qsh[64];
    __shared__ float wred[4][8];
    __shared__ float wsum[4][8];
    __shared__ float headsSh[128];

    if (tid < 64) qsh[tid] =
        reinterpret_cast<const unsigned int*>(Qh + ((size_t)(b * NN + n)) * 128)[tid];
    __syncthreads();

    const int m0 = tid * 4;                         // thread owns m0..m0+3
    const size_t bn_off = ((size_t)(b * NN + n)) * NN;

    // layer-1 accumulators, streamed over h
    float y[4][8];
#pragma unroll
    for (int mo = 0; mo < 4; ++mo)
#pragma unroll
        for (int o = 0; o < 8; ++o) y[mo][o] = b1[o];

#pragma unroll 1
    for (int h = 0; h < 8; ++h) {
        const size_t idx = (size_t)h * HSTRIDE + bn_off + (size_t)m0;
        const float4 sv = *reinterpret_cast<const float4*>(st + idx);
        const float4 ov = *reinterpret_cast<const float4*>(oss + idx);
        *reinterpret_cast<float4*>(out + OFF_ST + idx)  = sv;   // st_edge passthrough
        *reinterpret_cast<float4*>(out + OFF_OSS + idx) = ov;   // oss passthrough
        const float svv[4] = {sv.x, sv.y, sv.z, sv.w};
        const float ovv[4] = {ov.x, ov.y, ov.z, ov.w};

        // QK^T for 4 m: k-pair packed, coalesced uint4 loads (4 consecutive n)
        const unsigned int* kb = Kp + ((size_t)((b * NH + h) * 8)) * NN + m0;
        float acc[4] = {0.f, 0.f, 0.f, 0.f};
#pragma unroll
        for (int kp = 0; kp < 8; ++kp) {
            const uint4 k4 = *reinterpret_cast<const uint4*>(kb + (size_t)kp * NN);
            const unsigned int qp = qsh[h * 8 + kp];
            acc[0] = fdot2u(k4.x, qp, acc[0]);
            acc[1] = fdot2u(k4.y, qp, acc[1]);
            acc[2] = fdot2u(k4.z, qp, acc[2]);
            acc[3] = fdot2u(k4.w, qp, acc[3]);
        }

        float w1c[8], w1o[8];                       // uniform -> SGPRs
#pragma unroll
        for (int o = 0; o < 8; ++o) { w1c[o] = w1[o * 16 + h]; w1o[o] = w1[o * 16 + 8 + h]; }
#pragma unroll
        for (int mo = 0; mo < 4; ++mo) {
            const float c = (acc[mo] + svv[mo]) * 0.25f;   // (QK + st) * 1/sqrt(16)
#pragma unroll
            for (int o = 0; o < 8; ++o)
                y[mo][o] = fmaf(c, w1c[o], fmaf(ovv[mo], w1o[o], y[mo][o]));
        }
    }

    // ---- layer 2 -> f16 logits in LDS + per-thread max ----
    float lgv[8][4];
#pragma unroll
    for (int mo = 0; mo < 4; ++mo) {
        float z[8];
#pragma unroll
        for (int o = 0; o < 8; ++o) z[o] = fmaxf(y[mo][o], 0.f);
#pragma unroll
        for (int p = 0; p < 8; ++p) {
            float a = b2[p];
#pragma unroll
            for (int o = 0; o < 8; ++o) a = fmaf(z[o], w2[p * 8 + o], a);
            lgv[p][mo] = a;
        }
    }
    float tmax[8];
#pragma unroll
    for (int p = 0; p < 8; ++p) {
        union { uint2 u; half_t h4[4]; } pk;
#pragma unroll
        for (int mo = 0; mo < 4; ++mo) pk.h4[mo] = (half_t)lgv[p][mo];
        *reinterpret_cast<uint2*>(&lg[p * LGW + m0]) = pk.u;
        tmax[p] = fmaxf(fmaxf(lgv[p][0], lgv[p][1]), fmaxf(lgv[p][2], lgv[p][3]));
    }
#pragma unroll
    for (int p = 0; p < 8; ++p)
#pragma unroll
        for (int s = 32; s > 0; s >>= 1)
            tmax[p] = fmaxf(tmax[p], __shfl_xor(tmax[p], s));
    const int wv = tid >> 6;
    if ((tid & 63) == 0) {
#pragma unroll
        for (int p = 0; p < 8; ++p) wred[wv][p] = tmax[p];
    }
    __syncthreads();

    float bmax[8];
#pragma unroll
    for (int p = 0; p < 8; ++p)
        bmax[p] = fmaxf(fmaxf(wred[0][p], wred[1][p]), fmaxf(wred[2][p], wred[3][p]));

    // ---- exp in place (f16) + per-thread sums ----
    float psum[8];
#pragma unroll
    for (int p = 0; p < 8; ++p) {
        union { uint2 u; half_t h4[4]; } r;
        r.u = *reinterpret_cast<const uint2*>(&lg[p * LGW + m0]);
        const float e0 = __expf((float)r.h4[0] - bmax[p]);
        const float e1 = __expf((float)r.h4[1] - bmax[p]);
        const float e2 = __expf((float)r.h4[2] - bmax[p]);
        const float e3 = __expf((float)r.h4[3] - bmax[p]);
        psum[p] = (e0 + e1) + (e2 + e3);
        union { uint2 u; half_t h4[4]; } w;
        w.h4[0] = (half_t)e0; w.h4[1] = (half_t)e1;
        w.h4[2] = (half_t)e2; w.h4[3] = (half_t)e3;
        *reinterpret_cast<uint2*>(&lg[p * LGW + m0]) = w.u;
    }
#pragma unroll
    for (int p = 0; p < 8; ++p)
#pragma unroll
        for (int s = 32; s > 0; s >>= 1)
            psum[p] += __shfl_xor(psum[p], s);
    if ((tid & 63) == 0) {
#pragma unroll
        for (int p = 0; p < 8; ++p) wsum[wv][p] = psum[p];
    }
    __syncthreads();

    // ---- PV: 4 lanes share (h,vp); lane loads uint4 = 4 consecutive n of v-pair ----
    {
        const int g   = tid >> 2;          // 0..63 = h*8 + vp
        const int h   = g >> 3, vp = g & 7;
        const int sub = tid & 3;
        const unsigned int* vb = Vp + ((size_t)((b * NH + h) * 8 + vp)) * NN;
        float a0 = 0.f, a1 = 0.f;          // v = 2vp, 2vp+1
#pragma unroll 4
        for (int j = 0; j < 64; ++j) {
            const int nn = sub * 4 + 16 * j;
            const uint4 vv = *reinterpret_cast<const uint4*>(vb + nn);
            union { uint2 u; half_t h4[4]; } wr;
            wr.u = *reinterpret_cast<const uint2*>(&lg[h * LGW + nn]);
            const float w0 = (float)wr.h4[0], w1f = (float)wr.h4[1];
            const float w2f = (float)wr.h4[2], w3 = (float)wr.h4[3];
            union { unsigned int u; half2_t h2; } c;
            c.u = vv.x; a0 = fmaf(w0, (float)c.h2.x, a0); a1 = fmaf(w0, (float)c.h2.y, a1);
            c.u = vv.y; a0 = fmaf(w1f, (float)c.h2.x, a0); a1 = fmaf(w1f, (float)c.h2.y, a1);
            c.u = vv.z; a0 = fmaf(w2f, (float)c.h2.x, a0); a1 = fmaf(w2f, (float)c.h2.y, a1);
            c.u = vv.w; a0 = fmaf(w3, (float)c.h2.x, a0); a1 = fmaf(w3, (float)c.h2.y, a1);
        }
        a0 += __shfl_xor(a0, 1); a0 += __shfl_xor(a0, 2);
        a1 += __shfl_xor(a1, 1); a1 += __shfl_xor(a1, 2);
        if (sub == 0) {
            const float s = (wsum[0][h] + wsum[1][h]) + (wsum[2][h] + wsum[3][h]);
            const float r = 1.0f / s;
            headsSh[h * 16 + vp * 2 + 0] = a0 * r;
            headsSh[h * 16 + vp * 2 + 1] = a1 * r;
        }
    }
    __syncthreads();

    // ---- output projection: out[b,n,e] = sum_hv heads[hv] * Wout[hv,e] ----
    {
        const int e = tid & 127, hf2 = tid >> 7;
        float a = 0.f;
#pragma unroll
        for (int hv = 0; hv < 64; ++hv) {
            const int i = hf2 * 64 + hv;
            a = fmaf(headsSh[i], Wout[(size_t)i * 128 + e], a);
        }
        float* red = reinterpret_cast<float*>(lg);
        red[tid] = a;
        __syncthreads();
        if (tid < 128)
            out[((size_t)(b * NN + n)) * 128 + tid] = red[tid] + red[tid + 128];
    }
}

extern "C" void kernel_launch(void* const* d_in, const int* in_sizes, int n_in,
                              void* d_out, int out_size, void* d_ws, size_t ws_size,
                              hipStream_t stream) {
    const float* q    = (const float*)d_in[0];
    const float* oss  = (const float*)d_in[1];
    const float* st   = (const float*)d_in[2];
    const float* Wq   = (const float*)d_in[3];
    const float* Wk   = (const float*)d_in[4];
    const float* Wv   = (const float*)d_in[5];
    const float* w1   = (const float*)d_in[6];
    const float* b1   = (const float*)d_in[7];
    const float* w2   = (const float*)d_in[8];
    const float* b2   = (const float*)d_in[9];
    const float* Wout = (const float*)d_in[10];
    float* out = (float*)d_out;

    half_t* Qh = (half_t*)d_ws;                                   // 1 MB f16
    half_t* Kp = (half_t*)((char*)d_ws + 1u * 1024u * 1024u);     // 1 MB f16 (k-pair packed)
    half_t* Vp = (half_t*)((char*)d_ws + 2u * 1024u * 1024u);     // 1 MB f16 (v-pair packed)

    qkv_kernel<<<dim3(BB * NN), dim3(128), 0, stream>>>(q, Wq, Wk, Wv, Qh, Kp, Vp);
    fused_kernel<<<dim3(NN, BB), dim3(256), 0, stream>>>(
        oss, st, Qh, (const unsigned int*)Kp, (const unsigned int*)Vp,
        w1, b1, w2, b2, Wout, out);
}